// Round 5
// baseline (241.869 us; speedup 1.0000x reference)
//
#include <hip/hip_runtime.h>
#include <hip/hip_bf16.h>

#define NN 50000
#define NE 800000
#define DIM 128
#define SCAN_BLK 49   // ceil(50000/1024)

typedef __attribute__((ext_vector_type(8))) short short8_t;           // 8 bf16 for MFMA
typedef __attribute__((ext_vector_type(4))) float floatx4;
typedef __attribute__((ext_vector_type(2))) float floatx2;

static __device__ inline unsigned short f2bf(float x){        // RNE float->bf16
  unsigned int u = __float_as_uint(x);
  unsigned int r = (u + 0x7FFF + ((u >> 16) & 1)) >> 16;
  return (unsigned short)r;
}
static __device__ inline float bf2f(unsigned short u){
  return __uint_as_float(((unsigned int)u) << 16);
}

// ---- fp8 e4m3fn pack/unpack (HW path with guarded SW fallback) ----
#if __has_builtin(__builtin_amdgcn_cvt_pk_f32_fp8) && __has_builtin(__builtin_amdgcn_cvt_pk_fp8_f32)
#define HWFP8 1
#endif

static __device__ inline unsigned char fp8enc_sw(float x){
  unsigned int u = __float_as_uint(x);
  unsigned int s = (u >> 24) & 0x80u;
  float ax = fabsf(x);
  if (ax >= 448.f) return (unsigned char)(s | 0x7E);
  int exp = (int)((u >> 23) & 0xFF) - 127;
  if (exp < -9) return (unsigned char)s;
  if (exp < -6){
    int m = (int)(ax * 512.f + 0.5f);
    return (unsigned char)(s | m);
  }
  unsigned int mant = u & 0x7FFFFF;
  unsigned int keep = mant >> 20;
  unsigned int rest = mant & 0xFFFFF;
  if (rest > 0x80000u || (rest == 0x80000u && (keep & 1))){
    keep++;
    if (keep == 8){ keep = 0; exp++; }
  }
  if (exp > 8) return (unsigned char)(s | 0x7E);
  return (unsigned char)(s | ((unsigned)(exp + 7) << 3) | keep);
}
static __device__ inline float fp8dec_sw(unsigned char b){
  unsigned int s = ((unsigned int)(b & 0x80u)) << 24;
  unsigned int e = (b >> 3) & 0xF, m = b & 7;
  float v = (e == 0) ? (float)m * 0.001953125f
                     : __uint_as_float(((e + 120u) << 23) | (m << 20));
  return __uint_as_float(s | __float_as_uint(v));
}

static __device__ inline unsigned int fp8x4_enc(float a, float b, float c, float d){
#ifdef HWFP8
  int v = 0;
  v = __builtin_amdgcn_cvt_pk_fp8_f32(a, b, v, false);
  v = __builtin_amdgcn_cvt_pk_fp8_f32(c, d, v, true);
  return (unsigned int)v;
#else
  return (unsigned int)fp8enc_sw(a) | ((unsigned int)fp8enc_sw(b) << 8) |
         ((unsigned int)fp8enc_sw(c) << 16) | ((unsigned int)fp8enc_sw(d) << 24);
#endif
}
static __device__ inline void fp8x4_dec(unsigned int pk, float* o){
#ifdef HWFP8
  floatx2 lo = __builtin_amdgcn_cvt_pk_f32_fp8((int)pk, false);
  floatx2 hi = __builtin_amdgcn_cvt_pk_f32_fp8((int)pk, true);
  o[0] = lo[0]; o[1] = lo[1]; o[2] = hi[0]; o[3] = hi[1];
#else
  o[0] = fp8dec_sw(pk & 0xFF);         o[1] = fp8dec_sw((pk >> 8) & 0xFF);
  o[2] = fp8dec_sw((pk >> 16) & 0xFF); o[3] = fp8dec_sw((pk >> 24) & 0xFF);
#endif
}

// K0: heterogeneous setup. Block 0: fold W into attention vectors.
// Blocks 1..32: T f32 -> bf16. Blocks 33..228: zero count.
__global__ __launch_bounds__(256) void k_setup(const float* __restrict__ W,
                       const float* __restrict__ wb,
                       const float* __restrict__ aw, const float* __restrict__ ab,
                       float* __restrict__ v12c,
                       const float4* __restrict__ T4, ushort4* __restrict__ Tb4,
                       int* __restrict__ count){
  int b = blockIdx.x;
  int t = threadIdx.x;
  if (b == 0){
    __shared__ float r1[DIM], r2[DIM];
    if (t < DIM){
      float s1 = 0.f, s2 = 0.f;
      for (int j = 0; j < DIM; ++j){
        float w = W[j*DIM + t];
        s1 += aw[j] * w;
        s2 += aw[DIM + j] * w;
      }
      v12c[t] = s1;
      v12c[DIM + t] = s2;
      float bb = wb[t];
      r1[t] = bb * aw[t];
      r2[t] = bb * aw[DIM + t];
    }
    __syncthreads();
    if (t == 0){
      float a1s = 0.f, a2s = 0.f;
      for (int j = 0; j < DIM; ++j){ a1s += r1[j]; a2s += r2[j]; }
      v12c[2*DIM]   = a1s + ab[0];
      v12c[2*DIM+1] = a2s;
    }
  } else if (b <= 32){
    int i = (b-1)*256 + t;              // 8192 float4s of T
    float4 v = T4[i];
    Tb4[i] = make_ushort4(f2bf(v.x), f2bf(v.y), f2bf(v.z), f2bf(v.w));
  } else {
    int i = (b-33)*256 + t;
    if (i < NN) count[i] = 0;
  }
}

// K1: p1/p2 per node + bf16 emb copy + fp8 emb copy + fused histogram whose
// atomicAdd return value is the edge's within-row rank.
__global__ __launch_bounds__(256) void k_pvec(const float4* __restrict__ emb4,
                      const float* __restrict__ v12c,
                      float* __restrict__ p1, float* __restrict__ p2,
                      unsigned short* __restrict__ embh,
                      unsigned int* __restrict__ embf8,
                      const int* __restrict__ dst, int* __restrict__ count,
                      int* __restrict__ rank){
  int tid = blockIdx.x * 256 + threadIdx.x;
  if (tid < NE) rank[tid] = atomicAdd(&count[dst[tid]], 1);
  int g = threadIdx.x & 31;
  int i = blockIdx.x * 8 + (threadIdx.x >> 5);
  if (i >= NN) return;
  float4 e = emb4[i*32 + g];
  *(ushort4*)(embh + i*DIM + g*4) =
      make_ushort4(f2bf(e.x), f2bf(e.y), f2bf(e.z), f2bf(e.w));
  embf8[i*32 + g] = fp8x4_enc(e.x, e.y, e.z, e.w);
  float4 a = ((const float4*)v12c)[g];
  float4 b = ((const float4*)v12c)[32 + g];
  float s1 = e.x*a.x + e.y*a.y + e.z*a.z + e.w*a.w;
  float s2 = e.x*b.x + e.y*b.y + e.z*b.z + e.w*b.w;
  #pragma unroll
  for (int off = 16; off; off >>= 1){
    s1 += __shfl_down(s1, off, 32);
    s2 += __shfl_down(s2, off, 32);
  }
  if (g == 0){
    p1[i] = s1 + v12c[256];
    p2[i] = s2 + v12c[257];
  }
}

// K2: block-level exclusive scan (shuffle-based), block totals -> bsum
__global__ __launch_bounds__(1024) void k_scanA(const int* __restrict__ count,
                                                int* __restrict__ rowptr,
                                                int* __restrict__ bsum){
  __shared__ int wsum[16];
  int t = threadIdx.x;
  int i = blockIdx.x * 1024 + t;
  int v = (i < NN) ? count[i] : 0;
  int incl = v;
  int lane = t & 63;
  #pragma unroll
  for (int off = 1; off < 64; off <<= 1){
    int u = __shfl_up(incl, off, 64);
    if (lane >= off) incl += u;
  }
  int wid = t >> 6;
  if (lane == 63) wsum[wid] = incl;
  __syncthreads();
  if (t < 64){
    int x = (t < 16) ? wsum[t] : 0;
    int xi = x;
    #pragma unroll
    for (int off = 1; off < 16; off <<= 1){
      int u = __shfl_up(xi, off, 64);
      if (t >= off) xi += u;
    }
    if (t < 16) wsum[t] = xi - x;
  }
  __syncthreads();
  int excl = incl - v + wsum[wid];
  if (i < NN) rowptr[i] = excl;
  if (t == 1023) bsum[blockIdx.x] = excl + v;
}

// K3: fused scanB+C — every block redundantly wave-scans the 49 block sums,
// then adds the offset to its rowptr slice.
__global__ __launch_bounds__(256) void k_scanBC(int* __restrict__ rowptr,
                                                const int* __restrict__ bsum){
  __shared__ int boff[64];
  int t = threadIdx.x;
  if (t < 64){
    int v = (t < SCAN_BLK) ? bsum[t] : 0;
    int incl = v;
    #pragma unroll
    for (int off = 1; off < 64; off <<= 1){
      int u = __shfl_up(incl, off, 64);
      if (t >= off) incl += u;
    }
    boff[t] = incl - v;
  }
  __syncthreads();
  int i = blockIdx.x * 256 + t;
  if (i < NN) rowptr[i] += boff[i >> 10];
  if (i == 0) rowptr[NN] = NE;
}

// K4: atomic-free scatter: pos = rowptr[d] + rank[e]; one random 4B store.
__global__ __launch_bounds__(256) void k_scatter(const int* __restrict__ dst,
                        const int* __restrict__ src, const int* __restrict__ rank,
                        const int* __restrict__ rowptr, int* __restrict__ csr_src){
  int e = blockIdx.x * 256 + threadIdx.x;
  if (e >= NE) return;
  int d = dst[e];
  csr_src[rowptr[d] + rank[e]] = src[e];
}

// K5: FUSED gather + MFMA GEMM + LayerNorm.
// Block = 4 waves; wave w owns nodes nodebase..nodebase+15 (a full 16-row MFMA tile).
// Phase 1: wave gathers its 16 agg rows (fp8 source, 16 lanes x 8B, 4 edges in
// flight) into a wave-private bf16 LDS tile. Phase 2: h = [embh|tile] @ Tb^T + tb,
// MFMA, fused LN epilogue.
__global__ __launch_bounds__(256) void k_gatherout(
    const int* __restrict__ rowptr, const int* __restrict__ csr_src,
    const float* __restrict__ p1, const float* __restrict__ p2,
    const unsigned char* __restrict__ embf8,
    const unsigned short* __restrict__ embh,
    const unsigned short* __restrict__ Tb,
    const float* __restrict__ tb, const float* __restrict__ gamma,
    const float* __restrict__ beta, float* __restrict__ out){
  __shared__ unsigned short aggt[4][16][136];   // per-wave tile, padded rows
  int t = threadIdx.x;
  int w = t >> 6;
  int lane = t & 63;
  int c16 = lane & 15;                 // column group (8 values each)
  int slot = lane >> 4;                // edge slot 0..3
  int nodebase = blockIdx.x * 64 + w * 16;
  unsigned short* tile = &aggt[w][0][0];

  // ---- Phase 1: gather 16 nodes ----
  for (int j = 0; j < 16; ++j){
    int n = nodebase + j;
    float acc[8] = {0.f,0.f,0.f,0.f,0.f,0.f,0.f,0.f};
    float dsum = 0.f;
    if (n < NN){
      int s0 = rowptr[n], s1 = rowptr[n+1];
      float p1n = p1[n];
      for (int e = s0 + slot; e < s1; e += 4){
        int s = csr_src[e];                       // broadcast per 16-lane group
        float sc = p1n + p2[s];                   // L2-resident 200 KB
        sc = sc > 0.f ? sc : 0.2f * sc;
        float a = __expf(sc);
        dsum += a;
        uint2 pk = *(const uint2*)(embf8 + s*DIM + c16*8);  // 128B row / 16 lanes
        float vd[8];
        fp8x4_dec(pk.x, vd);
        fp8x4_dec(pk.y, vd + 4);
        #pragma unroll
        for (int u = 0; u < 8; ++u) acc[u] += a * vd[u];
      }
    }
    #pragma unroll
    for (int u = 0; u < 8; ++u){
      acc[u] += __shfl_xor(acc[u], 16, 64);
      acc[u] += __shfl_xor(acc[u], 32, 64);
    }
    dsum += __shfl_xor(dsum, 16, 64);
    dsum += __shfl_xor(dsum, 32, 64);
    if (slot == 0){
      float dinv = 1.0f / (dsum + 1e-20f);
      unsigned short o[8];
      #pragma unroll
      for (int u = 0; u < 8; ++u) o[u] = f2bf(acc[u] * dinv);
      *(short8_t*)(tile + j*136 + c16*8) = *(short8_t*)o;   // 16B LDS store
    }
  }
  __syncthreads();   // order LDS writes before reads (cheap, once)

  // ---- Phase 2: MFMA + LN (wave-private 16-node tile) ----
  int m16 = c16;
  int q = slot;
  int nA = nodebase + m16;
  int nAc = (nA < NN) ? nA : 0;
  floatx4 accm[8];
  #pragma unroll
  for (int ct = 0; ct < 8; ++ct) accm[ct] = (floatx4){0.f, 0.f, 0.f, 0.f};

  #pragma unroll
  for (int kc = 0; kc < 8; ++kc){
    int k0 = kc*32 + q*8;
    short8_t afrag;
    if (kc < 4) afrag = *(const short8_t*)(embh + nAc*DIM + k0);
    else        afrag = *(const short8_t*)(tile + m16*136 + (k0 - 128));
    #pragma unroll
    for (int ct = 0; ct < 8; ++ct){
      short8_t bfrag = *(const short8_t*)(Tb + (ct*16 + m16)*256 + k0);
      accm[ct] = __builtin_amdgcn_mfma_f32_16x16x32_bf16(afrag, bfrag, accm[ct], 0, 0, 0);
    }
  }

  float tbv[8], gmv[8], btv[8];
  #pragma unroll
  for (int ct = 0; ct < 8; ++ct){
    int col = ct*16 + m16;
    tbv[ct] = tb[col]; gmv[ct] = gamma[col]; btv[ct] = beta[col];
  }
  #pragma unroll
  for (int r = 0; r < 4; ++r){
    int n = nodebase + q*4 + r;              // D row = q*4 + reg
    float h[8]; float s = 0.f, ss = 0.f;
    #pragma unroll
    for (int ct = 0; ct < 8; ++ct){
      h[ct] = accm[ct][r] + tbv[ct];
      s += h[ct]; ss += h[ct]*h[ct];
    }
    #pragma unroll
    for (int off = 1; off < 16; off <<= 1){
      s  += __shfl_xor(s,  off, 16);
      ss += __shfl_xor(ss, off, 16);
    }
    float mu = s * (1.f/128.f);
    float var = ss * (1.f/128.f) - mu*mu;
    float rstd = rsqrtf(var + 1e-5f);
    if (n < NN){
      #pragma unroll
      for (int ct = 0; ct < 8; ++ct){
        out[n*DIM + ct*16 + m16] = (h[ct]-mu)*rstd*gmv[ct] + btv[ct];
      }
    }
  }
}

extern "C" void kernel_launch(void* const* d_in, const int* in_sizes, int n_in,
                              void* d_out, int out_size, void* d_ws, size_t ws_size,
                              hipStream_t stream){
  const float* emb          = (const float*)d_in[0];
  const int*   edges        = (const int*)d_in[1];
  const float* w_weight     = (const float*)d_in[2];
  const float* w_bias       = (const float*)d_in[3];
  const float* a_weight     = (const float*)d_in[4];
  const float* a_bias       = (const float*)d_in[5];
  const float* trans_weight = (const float*)d_in[6];
  const float* trans_bias   = (const float*)d_in[7];
  const float* ln_gamma     = (const float*)d_in[8];
  const float* ln_beta      = (const float*)d_in[9];
  float* out = (float*)d_out;

  // ws layout (float offsets):
  // p1[50k] p2[50k] v12c[320] | ints: count[50k] rowptr[50064] bsum[64]
  //   rank[800k] csr_src[800k] | embh bf16[6.4M] | Tb bf16[32768] | embf8 u8[6.4M]
  float* ws      = (float*)d_ws;
  float* p1      = ws;
  float* p2      = ws + 50000;
  float* v12c    = ws + 100000;
  int*   ibase   = (int*)(ws + 100320);
  int*   count   = ibase;
  int*   rowptr  = ibase + 50000;
  int*   bsum    = ibase + 100064;
  int*   rank    = ibase + 100128;
  int*   csr_src = ibase + 900128;
  unsigned short* embh  = (unsigned short*)(ws + 1800448);
  unsigned short* Tb    = (unsigned short*)(ws + 5000448);
  unsigned int*   embf8 = (unsigned int*)(ws + 5016832);

  const int* e_dst = edges;
  const int* e_src = edges + NE;

  k_setup<<<229, 256, 0, stream>>>(w_weight, w_bias, a_weight, a_bias, v12c,
                                   (const float4*)trans_weight, (ushort4*)Tb, count);
  k_pvec<<<(NN + 7)/8, 256, 0, stream>>>((const float4*)emb, v12c, p1, p2,
                                         embh, embf8, e_dst, count, rank);
  k_scanA<<<SCAN_BLK, 1024, 0, stream>>>(count, rowptr, bsum);
  k_scanBC<<<(NN + 255)/256, 256, 0, stream>>>(rowptr, bsum);
  k_scatter<<<(NE + 255)/256, 256, 0, stream>>>(e_dst, e_src, rank, rowptr, csr_src);
  k_gatherout<<<(NN + 63)/64, 256, 0, stream>>>(rowptr, csr_src, p1, p2,
                                                (const unsigned char*)embf8, embh, Tb,
                                                trans_bias, ln_gamma, ln_beta, out);
}

// Round 6
// 229.252 us; speedup vs baseline: 1.0550x; 1.0550x over previous
//
#include <hip/hip_runtime.h>
#include <hip/hip_bf16.h>

#define NN 50000
#define NE 800000
#define DIM 128
#define SCAN_BLK 49   // ceil(50000/1024)

typedef __attribute__((ext_vector_type(8))) short short8_t;           // 8 bf16 for MFMA
typedef __attribute__((ext_vector_type(8))) unsigned short ushort8_t;
typedef __attribute__((ext_vector_type(4))) float floatx4;
typedef __attribute__((ext_vector_type(2))) float floatx2;

static __device__ inline unsigned short f2bf(float x){        // RNE float->bf16
  unsigned int u = __float_as_uint(x);
  unsigned int r = (u + 0x7FFF + ((u >> 16) & 1)) >> 16;
  return (unsigned short)r;
}

// ---- fp8 e4m3fn pack/unpack (HW path with guarded SW fallback) ----
#if __has_builtin(__builtin_amdgcn_cvt_pk_f32_fp8) && __has_builtin(__builtin_amdgcn_cvt_pk_fp8_f32)
#define HWFP8 1
#endif

static __device__ inline unsigned char fp8enc_sw(float x){
  unsigned int u = __float_as_uint(x);
  unsigned int s = (u >> 24) & 0x80u;
  float ax = fabsf(x);
  if (ax >= 448.f) return (unsigned char)(s | 0x7E);
  int exp = (int)((u >> 23) & 0xFF) - 127;
  if (exp < -9) return (unsigned char)s;
  if (exp < -6){
    int m = (int)(ax * 512.f + 0.5f);
    return (unsigned char)(s | m);
  }
  unsigned int mant = u & 0x7FFFFF;
  unsigned int keep = mant >> 20;
  unsigned int rest = mant & 0xFFFFF;
  if (rest > 0x80000u || (rest == 0x80000u && (keep & 1))){
    keep++;
    if (keep == 8){ keep = 0; exp++; }
  }
  if (exp > 8) return (unsigned char)(s | 0x7E);
  return (unsigned char)(s | ((unsigned)(exp + 7) << 3) | keep);
}
static __device__ inline float fp8dec_sw(unsigned char b){
  unsigned int s = ((unsigned int)(b & 0x80u)) << 24;
  unsigned int e = (b >> 3) & 0xF, m = b & 7;
  float v = (e == 0) ? (float)m * 0.001953125f
                     : __uint_as_float(((e + 120u) << 23) | (m << 20));
  return __uint_as_float(s | __float_as_uint(v));
}

static __device__ inline unsigned int fp8x4_enc(float a, float b, float c, float d){
#ifdef HWFP8
  int v = 0;
  v = __builtin_amdgcn_cvt_pk_fp8_f32(a, b, v, false);
  v = __builtin_amdgcn_cvt_pk_fp8_f32(c, d, v, true);
  return (unsigned int)v;
#else
  return (unsigned int)fp8enc_sw(a) | ((unsigned int)fp8enc_sw(b) << 8) |
         ((unsigned int)fp8enc_sw(c) << 16) | ((unsigned int)fp8enc_sw(d) << 24);
#endif
}
static __device__ inline void fp8x4_dec(unsigned int pk, float* o){
#ifdef HWFP8
  floatx2 lo = __builtin_amdgcn_cvt_pk_f32_fp8((int)pk, false);
  floatx2 hi = __builtin_amdgcn_cvt_pk_f32_fp8((int)pk, true);
  o[0] = lo[0]; o[1] = lo[1]; o[2] = hi[0]; o[3] = hi[1];
#else
  o[0] = fp8dec_sw(pk & 0xFF);         o[1] = fp8dec_sw((pk >> 8) & 0xFF);
  o[2] = fp8dec_sw((pk >> 16) & 0xFF); o[3] = fp8dec_sw((pk >> 24) & 0xFF);
#endif
}

// wave-scan of the 49 block sums into an exclusive-offset LDS table (threads 0..63)
static __device__ inline void scan_boff(const int* __restrict__ bsum, int* __restrict__ boff){
  int t = threadIdx.x;
  if (t < 64){
    int v = (t < SCAN_BLK) ? bsum[t] : 0;
    int incl = v;
    #pragma unroll
    for (int off = 1; off < 64; off <<= 1){
      int u = __shfl_up(incl, off, 64);
      if (t >= off) incl += u;
    }
    boff[t] = incl - v;
  }
  __syncthreads();
}

// K0: heterogeneous setup. Block 0: fold W into attention vectors.
// Blocks 1..32: T f32 -> bf16. Blocks 33..228: zero count.
__global__ __launch_bounds__(256) void k_setup(const float* __restrict__ W,
                       const float* __restrict__ wb,
                       const float* __restrict__ aw, const float* __restrict__ ab,
                       float* __restrict__ v12c,
                       const float4* __restrict__ T4, ushort4* __restrict__ Tb4,
                       int* __restrict__ count){
  int b = blockIdx.x;
  int t = threadIdx.x;
  if (b == 0){
    __shared__ float r1[DIM], r2[DIM];
    if (t < DIM){
      float s1 = 0.f, s2 = 0.f;
      for (int j = 0; j < DIM; ++j){
        float w = W[j*DIM + t];
        s1 += aw[j] * w;
        s2 += aw[DIM + j] * w;
      }
      v12c[t] = s1;
      v12c[DIM + t] = s2;
      float bb = wb[t];
      r1[t] = bb * aw[t];
      r2[t] = bb * aw[DIM + t];
    }
    __syncthreads();
    if (t == 0){
      float a1s = 0.f, a2s = 0.f;
      for (int j = 0; j < DIM; ++j){ a1s += r1[j]; a2s += r2[j]; }
      v12c[2*DIM]   = a1s + ab[0];
      v12c[2*DIM+1] = a2s;
    }
  } else if (b <= 32){
    int i = (b-1)*256 + t;              // 8192 float4s of T
    float4 v = T4[i];
    Tb4[i] = make_ushort4(f2bf(v.x), f2bf(v.y), f2bf(v.z), f2bf(v.w));
  } else {
    int i = (b-33)*256 + t;
    if (i < NN) count[i] = 0;
  }
}

// K1: p1/p2 per node + bf16 emb copy + fp8 emb copy + fused histogram whose
// atomicAdd return value is the edge's within-row rank.
__global__ __launch_bounds__(256) void k_pvec(const float4* __restrict__ emb4,
                      const float* __restrict__ v12c,
                      float* __restrict__ p1, float* __restrict__ p2,
                      unsigned short* __restrict__ embh,
                      unsigned int* __restrict__ embf8,
                      const int* __restrict__ dst, int* __restrict__ count,
                      int* __restrict__ rank){
  int tid = blockIdx.x * 256 + threadIdx.x;
  if (tid < NE) rank[tid] = atomicAdd(&count[dst[tid]], 1);
  int g = threadIdx.x & 31;
  int i = blockIdx.x * 8 + (threadIdx.x >> 5);
  if (i >= NN) return;
  float4 e = emb4[i*32 + g];
  *(ushort4*)(embh + i*DIM + g*4) =
      make_ushort4(f2bf(e.x), f2bf(e.y), f2bf(e.z), f2bf(e.w));
  embf8[i*32 + g] = fp8x4_enc(e.x, e.y, e.z, e.w);
  float4 a = ((const float4*)v12c)[g];
  float4 b = ((const float4*)v12c)[32 + g];
  float s1 = e.x*a.x + e.y*a.y + e.z*a.z + e.w*a.w;
  float s2 = e.x*b.x + e.y*b.y + e.z*b.z + e.w*b.w;
  #pragma unroll
  for (int off = 16; off; off >>= 1){
    s1 += __shfl_down(s1, off, 32);
    s2 += __shfl_down(s2, off, 32);
  }
  if (g == 0){
    p1[i] = s1 + v12c[256];
    p2[i] = s2 + v12c[257];
  }
}

// K2: block-level exclusive scan (shuffle-based), block totals -> bsum
__global__ __launch_bounds__(1024) void k_scanA(const int* __restrict__ count,
                                                int* __restrict__ rowptr,
                                                int* __restrict__ bsum){
  __shared__ int wsum[16];
  int t = threadIdx.x;
  int i = blockIdx.x * 1024 + t;
  int v = (i < NN) ? count[i] : 0;
  int incl = v;
  int lane = t & 63;
  #pragma unroll
  for (int off = 1; off < 64; off <<= 1){
    int u = __shfl_up(incl, off, 64);
    if (lane >= off) incl += u;
  }
  int wid = t >> 6;
  if (lane == 63) wsum[wid] = incl;
  __syncthreads();
  if (t < 64){
    int x = (t < 16) ? wsum[t] : 0;
    int xi = x;
    #pragma unroll
    for (int off = 1; off < 16; off <<= 1){
      int u = __shfl_up(xi, off, 64);
      if (t >= off) xi += u;
    }
    if (t < 16) wsum[t] = xi - x;
  }
  __syncthreads();
  int excl = incl - v + wsum[wid];
  if (i < NN) rowptr[i] = excl;        // block-local exclusive (boff applied by consumers)
  if (t == 1023) bsum[blockIdx.x] = excl + v;
}

// K3: atomic-free scatter; applies block offset inline (no scanBC pass).
__global__ __launch_bounds__(256) void k_scatter(const int* __restrict__ dst,
                        const int* __restrict__ src, const int* __restrict__ rank,
                        const int* __restrict__ rowptr, const int* __restrict__ bsum,
                        int* __restrict__ csr_src){
  __shared__ int boff[64];
  scan_boff(bsum, boff);
  int e = blockIdx.x * 256 + threadIdx.x;
  if (e >= NE) return;
  int d = dst[e];
  csr_src[rowptr[d] + boff[d >> 10] + rank[e]] = src[e];
}

// K4: one 64-lane wave per destination node, 8 edges in flight
// (8 lanes x 16B = one 128B fp8 row each). attn inline (p2 is L2-resident).
// fp32 accumulate, normalized bf16 row store.
__global__ __launch_bounds__(256) void k_gather(const int* __restrict__ rowptr,
                       const int* __restrict__ bsum,
                       const int* __restrict__ csr_src,
                       const float* __restrict__ p1, const float* __restrict__ p2,
                       const unsigned char* __restrict__ embf8,
                       unsigned short* __restrict__ aggh){
  __shared__ int boff[64];
  scan_boff(bsum, boff);
  int lane = threadIdx.x & 63;
  int c8 = lane & 7;                   // 16B slot within the 128B fp8 row
  int slot = lane >> 3;                // edge slot 0..7
  int n = blockIdx.x * 4 + (threadIdx.x >> 6);
  if (n >= NN) return;
  int s0 = rowptr[n] + boff[n >> 10];
  int s1 = (n+1 < NN) ? rowptr[n+1] + boff[(n+1) >> 10] : NE;
  float p1n = p1[n];
  float acc[16];
  #pragma unroll
  for (int u = 0; u < 16; ++u) acc[u] = 0.f;
  float dsum = 0.f;
  for (int e = s0 + slot; e < s1; e += 8){
    int s = csr_src[e];                              // broadcast per 8-lane group
    float sc = p1n + p2[s];                          // L2-resident 200 KB
    sc = sc > 0.f ? sc : 0.2f * sc;
    float a = __expf(sc);
    dsum += a;
    uint4 pk = *(const uint4*)(embf8 + (size_t)s*DIM + c8*16);   // 16B/lane
    float vd[16];
    fp8x4_dec(pk.x, vd);
    fp8x4_dec(pk.y, vd + 4);
    fp8x4_dec(pk.z, vd + 8);
    fp8x4_dec(pk.w, vd + 12);
    #pragma unroll
    for (int u = 0; u < 16; ++u) acc[u] += a * vd[u];
  }
  #pragma unroll
  for (int u = 0; u < 16; ++u){
    acc[u] += __shfl_xor(acc[u], 8, 64);
    acc[u] += __shfl_xor(acc[u], 16, 64);
    acc[u] += __shfl_xor(acc[u], 32, 64);
  }
  dsum += __shfl_xor(dsum, 8, 64);
  dsum += __shfl_xor(dsum, 16, 64);
  dsum += __shfl_xor(dsum, 32, 64);
  if (slot == 0){
    float dinv = 1.0f / (dsum + 1e-20f);
    unsigned short o[16];
    #pragma unroll
    for (int u = 0; u < 16; ++u) o[u] = f2bf(acc[u] * dinv);
    *(ushort8_t*)(aggh + n*DIM + c8*16)     = *(ushort8_t*)o;
    *(ushort8_t*)(aggh + n*DIM + c8*16 + 8) = *(ushort8_t*)(o + 8);
  }
}

// K5: MFMA GEMM h = [embh|aggh] @ Tb^T + tb, fused LayerNorm.
// Block = 4 waves x 16 nodes; barrier-free, B frags L2-broadcast.
__global__ __launch_bounds__(256) void k_out(const unsigned short* __restrict__ embh,
                     const unsigned short* __restrict__ aggh,
                     const unsigned short* __restrict__ Tb,
                     const float* __restrict__ tb,
                     const float* __restrict__ gamma, const float* __restrict__ beta,
                     float* __restrict__ out){
  int t = threadIdx.x;
  int w = t >> 6;
  int lane = t & 63;
  int m16 = lane & 15;
  int q = lane >> 4;                         // 0..3
  int nodebase = blockIdx.x * 64 + w * 16;
  int nA = nodebase + m16;
  int nAc = (nA < NN) ? nA : 0;              // clamp loads; stores guarded
  floatx4 acc[8];
  #pragma unroll
  for (int ct = 0; ct < 8; ++ct) acc[ct] = (floatx4){0.f, 0.f, 0.f, 0.f};

  #pragma unroll
  for (int kc = 0; kc < 8; ++kc){
    int k0 = kc*32 + q*8;
    const unsigned short* aptr = (kc < 4) ? (embh + nAc*DIM + k0)
                                          : (aggh + nAc*DIM + (k0 - 128));
    short8_t afrag = *(const short8_t*)aptr;           // A[m=m16][k0..k0+7]
    #pragma unroll
    for (int ct = 0; ct < 8; ++ct){
      short8_t bfrag = *(const short8_t*)(Tb + (ct*16 + m16)*256 + k0); // B[k][j]=T[j][k]
      acc[ct] = __builtin_amdgcn_mfma_f32_16x16x32_bf16(afrag, bfrag, acc[ct], 0, 0, 0);
    }
  }

  float tbv[8], gmv[8], btv[8];
  #pragma unroll
  for (int ct = 0; ct < 8; ++ct){
    int col = ct*16 + m16;
    tbv[ct] = tb[col]; gmv[ct] = gamma[col]; btv[ct] = beta[col];
  }
  #pragma unroll
  for (int r = 0; r < 4; ++r){
    int n = nodebase + q*4 + r;              // D row = q*4 + reg
    float h[8]; float s = 0.f, ss = 0.f;
    #pragma unroll
    for (int ct = 0; ct < 8; ++ct){
      h[ct] = acc[ct][r] + tbv[ct];
      s += h[ct]; ss += h[ct]*h[ct];
    }
    #pragma unroll
    for (int off = 1; off < 16; off <<= 1){
      s  += __shfl_xor(s,  off, 16);
      ss += __shfl_xor(ss, off, 16);
    }
    float mu = s * (1.f/128.f);
    float var = ss * (1.f/128.f) - mu*mu;
    float rstd = rsqrtf(var + 1e-5f);
    if (n < NN){
      #pragma unroll
      for (int ct = 0; ct < 8; ++ct){
        out[n*DIM + ct*16 + m16] = (h[ct]-mu)*rstd*gmv[ct] + btv[ct];
      }
    }
  }
}

extern "C" void kernel_launch(void* const* d_in, const int* in_sizes, int n_in,
                              void* d_out, int out_size, void* d_ws, size_t ws_size,
                              hipStream_t stream){
  const float* emb          = (const float*)d_in[0];
  const int*   edges        = (const int*)d_in[1];
  const float* w_weight     = (const float*)d_in[2];
  const float* w_bias       = (const float*)d_in[3];
  const float* a_weight     = (const float*)d_in[4];
  const float* a_bias       = (const float*)d_in[5];
  const float* trans_weight = (const float*)d_in[6];
  const float* trans_bias   = (const float*)d_in[7];
  const float* ln_gamma     = (const float*)d_in[8];
  const float* ln_beta      = (const float*)d_in[9];
  float* out = (float*)d_out;

  // ws layout (float offsets):
  // p1[50k] p2[50k] v12c[320] | ints: count[50k] rowptr[50064] bsum[64]
  //   rank[800k] csr_src[800k] | embh bf16[6.4M] | Tb bf16[32768]
  //   | aggh bf16[6.4M] | embf8 u32[1.6M]
  float* ws      = (float*)d_ws;
  float* p1      = ws;
  float* p2      = ws + 50000;
  float* v12c    = ws + 100000;
  int*   ibase   = (int*)(ws + 100320);
  int*   count   = ibase;
  int*   rowptr  = ibase + 50000;
  int*   bsum    = ibase + 100064;
  int*   rank    = ibase + 100128;
  int*   csr_src = ibase + 900128;
  unsigned short* embh  = (unsigned short*)(ws + 1800448);
  unsigned short* Tb    = (unsigned short*)(ws + 5000448);
  unsigned short* aggh  = (unsigned short*)(ws + 5016832);
  unsigned int*   embf8 = (unsigned int*)(ws + 8216832);

  const int* e_dst = edges;
  const int* e_src = edges + NE;

  k_setup<<<229, 256, 0, stream>>>(w_weight, w_bias, a_weight, a_bias, v12c,
                                   (const float4*)trans_weight, (ushort4*)Tb, count);
  k_pvec<<<(NN + 7)/8, 256, 0, stream>>>((const float4*)emb, v12c, p1, p2,
                                         embh, embf8, e_dst, count, rank);
  k_scanA<<<SCAN_BLK, 1024, 0, stream>>>(count, rowptr, bsum);
  k_scatter<<<(NE + 255)/256, 256, 0, stream>>>(e_dst, e_src, rank, rowptr, bsum, csr_src);
  k_gather<<<(NN + 3)/4, 256, 0, stream>>>(rowptr, bsum, csr_src, p1, p2,
                                           (const unsigned char*)embf8, aggh);
  k_out<<<(NN + 63)/64, 256, 0, stream>>>(embh, aggh, Tb, trans_bias,
                                          ln_gamma, ln_beta, out);
}

// Round 8
// 226.224 us; speedup vs baseline: 1.0692x; 1.0134x over previous
//
#include <hip/hip_runtime.h>
#include <hip/hip_bf16.h>

#define NN 50000
#define NE 800000
#define DIM 128
#define SCAN_BLK 49   // ceil(50000/1024)

typedef __attribute__((ext_vector_type(8))) short short8_t;           // 8 bf16 for MFMA
typedef __attribute__((ext_vector_type(8))) unsigned short ushort8_t;
typedef __attribute__((ext_vector_type(4))) float floatx4;
typedef __attribute__((ext_vector_type(2))) float floatx2;

static __device__ inline unsigned short f2bf(float x){        // RNE float->bf16
  unsigned int u = __float_as_uint(x);
  unsigned int r = (u + 0x7FFF + ((u >> 16) & 1)) >> 16;
  return (unsigned short)r;
}

// ---- fp8 e4m3fn pack/unpack (HW path with guarded SW fallback) ----
#if __has_builtin(__builtin_amdgcn_cvt_pk_f32_fp8) && __has_builtin(__builtin_amdgcn_cvt_pk_fp8_f32)
#define HWFP8 1
#endif

static __device__ inline unsigned char fp8enc_sw(float x){
  unsigned int u = __float_as_uint(x);
  unsigned int s = (u >> 24) & 0x80u;
  float ax = fabsf(x);
  if (ax >= 448.f) return (unsigned char)(s | 0x7E);
  int exp = (int)((u >> 23) & 0xFF) - 127;
  if (exp < -9) return (unsigned char)s;
  if (exp < -6){
    int m = (int)(ax * 512.f + 0.5f);
    return (unsigned char)(s | m);
  }
  unsigned int mant = u & 0x7FFFFF;
  unsigned int keep = mant >> 20;
  unsigned int rest = mant & 0xFFFFF;
  if (rest > 0x80000u || (rest == 0x80000u && (keep & 1))){
    keep++;
    if (keep == 8){ keep = 0; exp++; }
  }
  if (exp > 8) return (unsigned char)(s | 0x7E);
  return (unsigned char)(s | ((unsigned)(exp + 7) << 3) | keep);
}
static __device__ inline float fp8dec_sw(unsigned char b){
  unsigned int s = ((unsigned int)(b & 0x80u)) << 24;
  unsigned int e = (b >> 3) & 0xF, m = b & 7;
  float v = (e == 0) ? (float)m * 0.001953125f
                     : __uint_as_float(((e + 120u) << 23) | (m << 20));
  return __uint_as_float(s | __float_as_uint(v));
}

static __device__ inline unsigned int fp8x4_enc(float a, float b, float c, float d){
#ifdef HWFP8
  int v = 0;
  v = __builtin_amdgcn_cvt_pk_fp8_f32(a, b, v, false);
  v = __builtin_amdgcn_cvt_pk_fp8_f32(c, d, v, true);
  return (unsigned int)v;
#else
  return (unsigned int)fp8enc_sw(a) | ((unsigned int)fp8enc_sw(b) << 8) |
         ((unsigned int)fp8enc_sw(c) << 16) | ((unsigned int)fp8enc_sw(d) << 24);
#endif
}
static __device__ inline void fp8x4_dec(unsigned int pk, float* o){
#ifdef HWFP8
  floatx2 lo = __builtin_amdgcn_cvt_pk_f32_fp8((int)pk, false);
  floatx2 hi = __builtin_amdgcn_cvt_pk_f32_fp8((int)pk, true);
  o[0] = lo[0]; o[1] = lo[1]; o[2] = hi[0]; o[3] = hi[1];
#else
  o[0] = fp8dec_sw(pk & 0xFF);         o[1] = fp8dec_sw((pk >> 8) & 0xFF);
  o[2] = fp8dec_sw((pk >> 16) & 0xFF); o[3] = fp8dec_sw((pk >> 24) & 0xFF);
#endif
}

// wave-scan of the 49 block sums into an exclusive-offset LDS table (threads 0..63)
static __device__ inline void scan_boff(const int* __restrict__ bsum, int* __restrict__ boff){
  int t = threadIdx.x;
  if (t < 64){
    int v = (t < SCAN_BLK) ? bsum[t] : 0;
    int incl = v;
    #pragma unroll
    for (int off = 1; off < 64; off <<= 1){
      int u = __shfl_up(incl, off, 64);
      if (t >= off) incl += u;
    }
    boff[t] = incl - v;
  }
  __syncthreads();
}

// K0: heterogeneous setup. Block 0: fold W into attention vectors.
// Blocks 1..32: T f32 -> bf16. Blocks 33..228: zero count.
__global__ __launch_bounds__(256) void k_setup(const float* __restrict__ W,
                       const float* __restrict__ wb,
                       const float* __restrict__ aw, const float* __restrict__ ab,
                       float* __restrict__ v12c,
                       const float4* __restrict__ T4, ushort4* __restrict__ Tb4,
                       int* __restrict__ count){
  int b = blockIdx.x;
  int t = threadIdx.x;
  if (b == 0){
    __shared__ float r1[DIM], r2[DIM];
    if (t < DIM){
      float s1 = 0.f, s2 = 0.f;
      for (int j = 0; j < DIM; ++j){
        float w = W[j*DIM + t];
        s1 += aw[j] * w;
        s2 += aw[DIM + j] * w;
      }
      v12c[t] = s1;
      v12c[DIM + t] = s2;
      float bb = wb[t];
      r1[t] = bb * aw[t];
      r2[t] = bb * aw[DIM + t];
    }
    __syncthreads();
    if (t == 0){
      float a1s = 0.f, a2s = 0.f;
      for (int j = 0; j < DIM; ++j){ a1s += r1[j]; a2s += r2[j]; }
      v12c[2*DIM]   = a1s + ab[0];
      v12c[2*DIM+1] = a2s;
    }
  } else if (b <= 32){
    int i = (b-1)*256 + t;              // 8192 float4s of T
    float4 v = T4[i];
    Tb4[i] = make_ushort4(f2bf(v.x), f2bf(v.y), f2bf(v.z), f2bf(v.w));
  } else {
    int i = (b-33)*256 + t;
    if (i < NN) count[i] = 0;
  }
}

// K1: p1/p2 per node + bf16 emb copy + fp8 emb copy + fused histogram whose
// atomicAdd return value is the edge's within-row rank.
__global__ __launch_bounds__(256) void k_pvec(const float4* __restrict__ emb4,
                      const float* __restrict__ v12c,
                      float* __restrict__ p1, float* __restrict__ p2,
                      unsigned short* __restrict__ embh,
                      unsigned int* __restrict__ embf8,
                      const int* __restrict__ dst, int* __restrict__ count,
                      int* __restrict__ rank){
  int tid = blockIdx.x * 256 + threadIdx.x;
  if (tid < NE) rank[tid] = atomicAdd(&count[dst[tid]], 1);
  int g = threadIdx.x & 31;
  int i = blockIdx.x * 8 + (threadIdx.x >> 5);
  if (i >= NN) return;
  float4 e = emb4[i*32 + g];
  *(ushort4*)(embh + i*DIM + g*4) =
      make_ushort4(f2bf(e.x), f2bf(e.y), f2bf(e.z), f2bf(e.w));
  embf8[i*32 + g] = fp8x4_enc(e.x, e.y, e.z, e.w);
  float4 a = ((const float4*)v12c)[g];
  float4 b = ((const float4*)v12c)[32 + g];
  float s1 = e.x*a.x + e.y*a.y + e.z*a.z + e.w*a.w;
  float s2 = e.x*b.x + e.y*b.y + e.z*b.z + e.w*b.w;
  #pragma unroll
  for (int off = 16; off; off >>= 1){
    s1 += __shfl_down(s1, off, 32);
    s2 += __shfl_down(s2, off, 32);
  }
  if (g == 0){
    p1[i] = s1 + v12c[256];
    p2[i] = s2 + v12c[257];
  }
}

// K2: block-level exclusive scan (shuffle-based), block totals -> bsum
__global__ __launch_bounds__(1024) void k_scanA(const int* __restrict__ count,
                                                int* __restrict__ rowptr,
                                                int* __restrict__ bsum){
  __shared__ int wsum[16];
  int t = threadIdx.x;
  int i = blockIdx.x * 1024 + t;
  int v = (i < NN) ? count[i] : 0;
  int incl = v;
  int lane = t & 63;
  #pragma unroll
  for (int off = 1; off < 64; off <<= 1){
    int u = __shfl_up(incl, off, 64);
    if (lane >= off) incl += u;
  }
  int wid = t >> 6;
  if (lane == 63) wsum[wid] = incl;
  __syncthreads();
  if (t < 64){
    int x = (t < 16) ? wsum[t] : 0;
    int xi = x;
    #pragma unroll
    for (int off = 1; off < 16; off <<= 1){
      int u = __shfl_up(xi, off, 64);
      if (t >= off) xi += u;
    }
    if (t < 16) wsum[t] = xi - x;
  }
  __syncthreads();
  int excl = incl - v + wsum[wid];
  if (i < NN) rowptr[i] = excl;        // block-local exclusive (boff applied by consumers)
  if (t == 1023) bsum[blockIdx.x] = excl + v;
}

// K3: atomic-free scatter; computes attn ONCE per edge here and stores
// packed int2 {src, attn-bits}. Block offset applied inline.
__global__ __launch_bounds__(256) void k_scatter(const int* __restrict__ dst,
                        const int* __restrict__ src, const int* __restrict__ rank,
                        const int* __restrict__ rowptr, const int* __restrict__ bsum,
                        const float* __restrict__ p1, const float* __restrict__ p2,
                        int2* __restrict__ csr){
  __shared__ int boff[64];
  scan_boff(bsum, boff);
  int e = blockIdx.x * 256 + threadIdx.x;
  if (e >= NE) return;
  int d = dst[e];
  int s = src[e];
  float sc = p1[d] + p2[s];                 // both L2-resident (200 KB each)
  sc = sc > 0.f ? sc : 0.2f * sc;
  float a = __expf(sc);
  csr[rowptr[d] + boff[d >> 10] + rank[e]] = make_int2(s, __float_as_int(a));
}

// K4: one 64-lane wave per destination node, 4 edges in flight
// (16 lanes x 8B uint2 = one 128B fp8 row each). Pure load+decode+FMA inner
// loop (attn precomputed). fp32 accumulate, normalized bf16 row store.
__global__ __launch_bounds__(256) void k_gather(const int* __restrict__ rowptr,
                       const int* __restrict__ bsum,
                       const int2* __restrict__ csr,
                       const unsigned int* __restrict__ embf8,
                       unsigned short* __restrict__ aggh){
  __shared__ int boff[64];
  scan_boff(bsum, boff);
  int lane = threadIdx.x & 63;
  int c16 = lane & 15;                 // 8B slot within the 128B fp8 row
  int slot = lane >> 4;                // edge slot 0..3
  int n = blockIdx.x * 4 + (threadIdx.x >> 6);
  if (n >= NN) return;
  int s0 = rowptr[n] + boff[n >> 10];
  int s1 = (n+1 < NN) ? rowptr[n+1] + boff[(n+1) >> 10] : NE;
  float acc[8] = {0.f,0.f,0.f,0.f,0.f,0.f,0.f,0.f};
  float dsum = 0.f;
  for (int e = s0 + slot; e < s1; e += 4){
    int2 ea = csr[e];                                // broadcast per 16-lane group
    float a = __int_as_float(ea.y);
    dsum += a;
    uint2 pk = *(const uint2*)(embf8 + ea.x*32 + c16*2);   // 8B/lane
    float vd[8];
    fp8x4_dec(pk.x, vd);
    fp8x4_dec(pk.y, vd + 4);
    #pragma unroll
    for (int u = 0; u < 8; ++u) acc[u] += a * vd[u];
  }
  #pragma unroll
  for (int u = 0; u < 8; ++u){
    acc[u] += __shfl_xor(acc[u], 16, 64);
    acc[u] += __shfl_xor(acc[u], 32, 64);
  }
  dsum += __shfl_xor(dsum, 16, 64);
  dsum += __shfl_xor(dsum, 32, 64);
  if (slot == 0){
    float dinv = 1.0f / (dsum + 1e-20f);
    unsigned short o[8];
    #pragma unroll
    for (int u = 0; u < 8; ++u) o[u] = f2bf(acc[u] * dinv);
    *(ushort8_t*)(aggh + n*DIM + c16*8) = *(ushort8_t*)o;   // 256B row / 16 lanes
  }
}

// K5: MFMA GEMM h = [embh|aggh] @ Tb^T + tb, fused LayerNorm.
// Block = 4 waves x 16 nodes; barrier-free, B frags L2-broadcast.
__global__ __launch_bounds__(256) void k_out(const unsigned short* __restrict__ embh,
                     const unsigned short* __restrict__ aggh,
                     const unsigned short* __restrict__ Tb,
                     const float* __restrict__ tb,
                     const float* __restrict__ gamma, const float* __restrict__ beta,
                     float* __restrict__ out){
  int t = threadIdx.x;
  int w = t >> 6;
  int lane = t & 63;
  int m16 = lane & 15;
  int q = lane >> 4;                         // 0..3
  int nodebase = blockIdx.x * 64 + w * 16;
  int nA = nodebase + m16;
  int nAc = (nA < NN) ? nA : 0;              // clamp loads; stores guarded
  floatx4 acc[8];
  #pragma unroll
  for (int ct = 0; ct < 8; ++ct) acc[ct] = (floatx4){0.f, 0.f, 0.f, 0.f};

  #pragma unroll
  for (int kc = 0; kc < 8; ++kc){
    int k0 = kc*32 + q*8;
    const unsigned short* aptr = (kc < 4) ? (embh + nAc*DIM + k0)
                                          : (aggh + nAc*DIM + (k0 - 128));
    short8_t afrag = *(const short8_t*)aptr;           // A[m=m16][k0..k0+7]
    #pragma unroll
    for (int ct = 0; ct < 8; ++ct){
      short8_t bfrag = *(const short8_t*)(Tb + (ct*16 + m16)*256 + k0); // B[k][j]=T[j][k]
      acc[ct] = __builtin_amdgcn_mfma_f32_16x16x32_bf16(afrag, bfrag, acc[ct], 0, 0, 0);
    }
  }

  float tbv[8], gmv[8], btv[8];
  #pragma unroll
  for (int ct = 0; ct < 8; ++ct){
    int col = ct*16 + m16;
    tbv[ct] = tb[col]; gmv[ct] = gamma[col]; btv[ct] = beta[col];
  }
  #pragma unroll
  for (int r = 0; r < 4; ++r){
    int n = nodebase + q*4 + r;              // D row = q*4 + reg
    float h[8]; float s = 0.f, ss = 0.f;
    #pragma unroll
    for (int ct = 0; ct < 8; ++ct){
      h[ct] = acc[ct][r] + tbv[ct];
      s += h[ct]; ss += h[ct]*h[ct];
    }
    #pragma unroll
    for (int off = 1; off < 16; off <<= 1){
      s  += __shfl_xor(s,  off, 16);
      ss += __shfl_xor(ss, off, 16);
    }
    float mu = s * (1.f/128.f);
    float var = ss * (1.f/128.f) - mu*mu;
    float rstd = rsqrtf(var + 1e-5f);
    if (n < NN){
      #pragma unroll
      for (int ct = 0; ct < 8; ++ct){
        out[n*DIM + ct*16 + m16] = (h[ct]-mu)*rstd*gmv[ct] + btv[ct];
      }
    }
  }
}

extern "C" void kernel_launch(void* const* d_in, const int* in_sizes, int n_in,
                              void* d_out, int out_size, void* d_ws, size_t ws_size,
                              hipStream_t stream){
  const float* emb          = (const float*)d_in[0];
  const int*   edges        = (const int*)d_in[1];
  const float* w_weight     = (const float*)d_in[2];
  const float* w_bias       = (const float*)d_in[3];
  const float* a_weight     = (const float*)d_in[4];
  const float* a_bias       = (const float*)d_in[5];
  const float* trans_weight = (const float*)d_in[6];
  const float* trans_bias   = (const float*)d_in[7];
  const float* ln_gamma     = (const float*)d_in[8];
  const float* ln_beta      = (const float*)d_in[9];
  float* out = (float*)d_out;

  // ws layout (float offsets) — all regions DISJOINT (R7 bug: csr overlapped embh):
  // [0       ) p1      50,000
  // [50000   ) p2      50,000
  // [100000  ) v12c       320
  // [100320  ) ints: count[50k] rowptr[50064] bsum[64] rank[800k]   (ends 1000448)
  // [1000448 ) csr int2[800k] = 1.6M ints                           (ends 2600448)
  // [2600448 ) embh bf16[6.4M] = 3.2M floats                        (ends 5800448)
  // [5800448 ) Tb bf16[32768] = 16384 floats                        (ends 5816832)
  // [5816832 ) aggh bf16[6.4M] = 3.2M floats                        (ends 9016832)
  // [9016832 ) embf8 u32[1.6M]                                      (ends 10616832 = 42.5 MB)
  float* ws      = (float*)d_ws;
  float* p1      = ws;
  float* p2      = ws + 50000;
  float* v12c    = ws + 100000;
  int*   ibase   = (int*)(ws + 100320);
  int*   count   = ibase;
  int*   rowptr  = ibase + 50000;
  int*   bsum    = ibase + 100064;
  int*   rank    = ibase + 100128;
  int2*  csr     = (int2*)(ws + 1000448);
  unsigned short* embh  = (unsigned short*)(ws + 2600448);
  unsigned short* Tb    = (unsigned short*)(ws + 5800448);
  unsigned short* aggh  = (unsigned short*)(ws + 5816832);
  unsigned int*   embf8 = (unsigned int*)(ws + 9016832);

  const int* e_dst = edges;
  const int* e_src = edges + NE;

  k_setup<<<229, 256, 0, stream>>>(w_weight, w_bias, a_weight, a_bias, v12c,
                                   (const float4*)trans_weight, (ushort4*)Tb, count);
  k_pvec<<<(NN + 7)/8, 256, 0, stream>>>((const float4*)emb, v12c, p1, p2,
                                         embh, embf8, e_dst, count, rank);
  k_scanA<<<SCAN_BLK, 1024, 0, stream>>>(count, rowptr, bsum);
  k_scatter<<<(NE + 255)/256, 256, 0, stream>>>(e_dst, e_src, rank, rowptr, bsum,
                                                p1, p2, csr);
  k_gather<<<(NN + 3)/4, 256, 0, stream>>>(rowptr, bsum, csr, embf8, aggh);
  k_out<<<(NN + 63)/64, 256, 0, stream>>>(embh, aggh, Tb, trans_bias,
                                          ln_gamma, ln_beta, out);
}

// Round 9
// 225.403 us; speedup vs baseline: 1.0730x; 1.0036x over previous
//
#include <hip/hip_runtime.h>
#include <hip/hip_bf16.h>

#define NN 50000
#define NE 800000
#define DIM 128
#define SCAN_BLK 49   // ceil(50000/1024)

typedef __attribute__((ext_vector_type(8))) short short8_t;           // 8 bf16 for MFMA
typedef __attribute__((ext_vector_type(8))) unsigned short ushort8_t;
typedef __attribute__((ext_vector_type(4))) float floatx4;
typedef __attribute__((ext_vector_type(2))) float floatx2;

static __device__ inline unsigned short f2bf(float x){        // RNE float->bf16
  unsigned int u = __float_as_uint(x);
  unsigned int r = (u + 0x7FFF + ((u >> 16) & 1)) >> 16;
  return (unsigned short)r;
}

// ---- fp8 e4m3fn pack/unpack (HW path with guarded SW fallback) ----
#if __has_builtin(__builtin_amdgcn_cvt_pk_f32_fp8) && __has_builtin(__builtin_amdgcn_cvt_pk_fp8_f32)
#define HWFP8 1
#endif

static __device__ inline unsigned char fp8enc_sw(float x){
  unsigned int u = __float_as_uint(x);
  unsigned int s = (u >> 24) & 0x80u;
  float ax = fabsf(x);
  if (ax >= 448.f) return (unsigned char)(s | 0x7E);
  int exp = (int)((u >> 23) & 0xFF) - 127;
  if (exp < -9) return (unsigned char)s;
  if (exp < -6){
    int m = (int)(ax * 512.f + 0.5f);
    return (unsigned char)(s | m);
  }
  unsigned int mant = u & 0x7FFFFF;
  unsigned int keep = mant >> 20;
  unsigned int rest = mant & 0xFFFFF;
  if (rest > 0x80000u || (rest == 0x80000u && (keep & 1))){
    keep++;
    if (keep == 8){ keep = 0; exp++; }
  }
  if (exp > 8) return (unsigned char)(s | 0x7E);
  return (unsigned char)(s | ((unsigned)(exp + 7) << 3) | keep);
}
static __device__ inline float fp8dec_sw(unsigned char b){
  unsigned int s = ((unsigned int)(b & 0x80u)) << 24;
  unsigned int e = (b >> 3) & 0xF, m = b & 7;
  float v = (e == 0) ? (float)m * 0.001953125f
                     : __uint_as_float(((e + 120u) << 23) | (m << 20));
  return __uint_as_float(s | __float_as_uint(v));
}

static __device__ inline unsigned int fp8x4_enc(float a, float b, float c, float d){
#ifdef HWFP8
  int v = 0;
  v = __builtin_amdgcn_cvt_pk_fp8_f32(a, b, v, false);
  v = __builtin_amdgcn_cvt_pk_fp8_f32(c, d, v, true);
  return (unsigned int)v;
#else
  return (unsigned int)fp8enc_sw(a) | ((unsigned int)fp8enc_sw(b) << 8) |
         ((unsigned int)fp8enc_sw(c) << 16) | ((unsigned int)fp8enc_sw(d) << 24);
#endif
}
static __device__ inline void fp8x4_dec(unsigned int pk, float* o){
#ifdef HWFP8
  floatx2 lo = __builtin_amdgcn_cvt_pk_f32_fp8((int)pk, false);
  floatx2 hi = __builtin_amdgcn_cvt_pk_f32_fp8((int)pk, true);
  o[0] = lo[0]; o[1] = lo[1]; o[2] = hi[0]; o[3] = hi[1];
#else
  o[0] = fp8dec_sw(pk & 0xFF);         o[1] = fp8dec_sw((pk >> 8) & 0xFF);
  o[2] = fp8dec_sw((pk >> 16) & 0xFF); o[3] = fp8dec_sw((pk >> 24) & 0xFF);
#endif
}

// wave-scan of the 49 block sums into an exclusive-offset LDS table (threads 0..63)
static __device__ inline void scan_boff(const int* __restrict__ bsum, int* __restrict__ boff){
  int t = threadIdx.x;
  if (t < 64){
    int v = (t < SCAN_BLK) ? bsum[t] : 0;
    int incl = v;
    #pragma unroll
    for (int off = 1; off < 64; off <<= 1){
      int u = __shfl_up(incl, off, 64);
      if (t >= off) incl += u;
    }
    boff[t] = incl - v;
  }
  __syncthreads();
}

// K0: heterogeneous setup. Block 0: fold W into attention vectors.
// Blocks 1..32: T f32 -> bf16. Blocks 33..3157: zero padded count (800k ints).
__global__ __launch_bounds__(256) void k_setup(const float* __restrict__ W,
                       const float* __restrict__ wb,
                       const float* __restrict__ aw, const float* __restrict__ ab,
                       float* __restrict__ v12c,
                       const float4* __restrict__ T4, ushort4* __restrict__ Tb4,
                       int* __restrict__ count){
  int b = blockIdx.x;
  int t = threadIdx.x;
  if (b == 0){
    __shared__ float r1[DIM], r2[DIM];
    if (t < DIM){
      float s1 = 0.f, s2 = 0.f;
      for (int j = 0; j < DIM; ++j){
        float w = W[j*DIM + t];
        s1 += aw[j] * w;
        s2 += aw[DIM + j] * w;
      }
      v12c[t] = s1;
      v12c[DIM + t] = s2;
      float bb = wb[t];
      r1[t] = bb * aw[t];
      r2[t] = bb * aw[DIM + t];
    }
    __syncthreads();
    if (t == 0){
      float a1s = 0.f, a2s = 0.f;
      for (int j = 0; j < DIM; ++j){ a1s += r1[j]; a2s += r2[j]; }
      v12c[2*DIM]   = a1s + ab[0];
      v12c[2*DIM+1] = a2s;
    }
  } else if (b <= 32){
    int i = (b-1)*256 + t;              // 8192 float4s of T
    float4 v = T4[i];
    Tb4[i] = make_ushort4(f2bf(v.x), f2bf(v.y), f2bf(v.z), f2bf(v.w));
  } else {
    int i = (b-33)*256 + t;             // zero 800,000 padded counters
    if (i < NN*16) count[i] = 0;
  }
}

// K1: p1/p2 per node + bf16 emb copy + fp8 emb copy + fused histogram.
// Counters padded to one per 64B cache line (count[d<<4]) to kill false-sharing
// serialization at the L2 atomic unit; atomicAdd return value = edge rank.
__global__ __launch_bounds__(256) void k_pvec(const float4* __restrict__ emb4,
                      const float* __restrict__ v12c,
                      float* __restrict__ p1, float* __restrict__ p2,
                      unsigned short* __restrict__ embh,
                      unsigned int* __restrict__ embf8,
                      const int* __restrict__ dst, int* __restrict__ count,
                      int* __restrict__ rank){
  int tid = blockIdx.x * 256 + threadIdx.x;
  if (tid < NE) rank[tid] = atomicAdd(&count[dst[tid] << 4], 1);
  int g = threadIdx.x & 31;
  int i = blockIdx.x * 8 + (threadIdx.x >> 5);
  if (i >= NN) return;
  float4 e = emb4[i*32 + g];
  *(ushort4*)(embh + i*DIM + g*4) =
      make_ushort4(f2bf(e.x), f2bf(e.y), f2bf(e.z), f2bf(e.w));
  embf8[i*32 + g] = fp8x4_enc(e.x, e.y, e.z, e.w);
  float4 a = ((const float4*)v12c)[g];
  float4 b = ((const float4*)v12c)[32 + g];
  float s1 = e.x*a.x + e.y*a.y + e.z*a.z + e.w*a.w;
  float s2 = e.x*b.x + e.y*b.y + e.z*b.z + e.w*b.w;
  #pragma unroll
  for (int off = 16; off; off >>= 1){
    s1 += __shfl_down(s1, off, 32);
    s2 += __shfl_down(s2, off, 32);
  }
  if (g == 0){
    p1[i] = s1 + v12c[256];
    p2[i] = s2 + v12c[257];
  }
}

// K2: block-level exclusive scan over the padded counters (stride-16 reads).
__global__ __launch_bounds__(1024) void k_scanA(const int* __restrict__ count,
                                                int* __restrict__ rowptr,
                                                int* __restrict__ bsum){
  __shared__ int wsum[16];
  int t = threadIdx.x;
  int i = blockIdx.x * 1024 + t;
  int v = (i < NN) ? count[i << 4] : 0;
  int incl = v;
  int lane = t & 63;
  #pragma unroll
  for (int off = 1; off < 64; off <<= 1){
    int u = __shfl_up(incl, off, 64);
    if (lane >= off) incl += u;
  }
  int wid = t >> 6;
  if (lane == 63) wsum[wid] = incl;
  __syncthreads();
  if (t < 64){
    int x = (t < 16) ? wsum[t] : 0;
    int xi = x;
    #pragma unroll
    for (int off = 1; off < 16; off <<= 1){
      int u = __shfl_up(xi, off, 64);
      if (t >= off) xi += u;
    }
    if (t < 16) wsum[t] = xi - x;
  }
  __syncthreads();
  int excl = incl - v + wsum[wid];
  if (i < NN) rowptr[i] = excl;        // block-local exclusive (boff applied by consumers)
  if (t == 1023) bsum[blockIdx.x] = excl + v;
}

// K3: atomic-free scatter; computes attn ONCE per edge here and stores
// packed int2 {src, attn-bits}. Block offset applied inline.
__global__ __launch_bounds__(256) void k_scatter(const int* __restrict__ dst,
                        const int* __restrict__ src, const int* __restrict__ rank,
                        const int* __restrict__ rowptr, const int* __restrict__ bsum,
                        const float* __restrict__ p1, const float* __restrict__ p2,
                        int2* __restrict__ csr){
  __shared__ int boff[64];
  scan_boff(bsum, boff);
  int e = blockIdx.x * 256 + threadIdx.x;
  if (e >= NE) return;
  int d = dst[e];
  int s = src[e];
  float sc = p1[d] + p2[s];                 // both L2-resident (200 KB each)
  sc = sc > 0.f ? sc : 0.2f * sc;
  float a = __expf(sc);
  csr[rowptr[d] + boff[d >> 10] + rank[e]] = make_int2(s, __float_as_int(a));
}

// K4: one 64-lane wave per destination node, 4 edges in flight
// (16 lanes x 8B uint2 = one 128B fp8 row each). Pure load+decode+FMA inner
// loop (attn precomputed). fp32 accumulate, normalized bf16 row store.
__global__ __launch_bounds__(256) void k_gather(const int* __restrict__ rowptr,
                       const int* __restrict__ bsum,
                       const int2* __restrict__ csr,
                       const unsigned int* __restrict__ embf8,
                       unsigned short* __restrict__ aggh){
  __shared__ int boff[64];
  scan_boff(bsum, boff);
  int lane = threadIdx.x & 63;
  int c16 = lane & 15;                 // 8B slot within the 128B fp8 row
  int slot = lane >> 4;                // edge slot 0..3
  int n = blockIdx.x * 4 + (threadIdx.x >> 6);
  if (n >= NN) return;
  int s0 = rowptr[n] + boff[n >> 10];
  int s1 = (n+1 < NN) ? rowptr[n+1] + boff[(n+1) >> 10] : NE;
  float acc[8] = {0.f,0.f,0.f,0.f,0.f,0.f,0.f,0.f};
  float dsum = 0.f;
  for (int e = s0 + slot; e < s1; e += 4){
    int2 ea = csr[e];                                // broadcast per 16-lane group
    float a = __int_as_float(ea.y);
    dsum += a;
    uint2 pk = *(const uint2*)(embf8 + ea.x*32 + c16*2);   // 8B/lane
    float vd[8];
    fp8x4_dec(pk.x, vd);
    fp8x4_dec(pk.y, vd + 4);
    #pragma unroll
    for (int u = 0; u < 8; ++u) acc[u] += a * vd[u];
  }
  #pragma unroll
  for (int u = 0; u < 8; ++u){
    acc[u] += __shfl_xor(acc[u], 16, 64);
    acc[u] += __shfl_xor(acc[u], 32, 64);
  }
  dsum += __shfl_xor(dsum, 16, 64);
  dsum += __shfl_xor(dsum, 32, 64);
  if (slot == 0){
    float dinv = 1.0f / (dsum + 1e-20f);
    unsigned short o[8];
    #pragma unroll
    for (int u = 0; u < 8; ++u) o[u] = f2bf(acc[u] * dinv);
    *(ushort8_t*)(aggh + n*DIM + c16*8) = *(ushort8_t*)o;   // 256B row / 16 lanes
  }
}

// K5: MFMA GEMM h = [embh|aggh] @ Tb^T + tb, fused LayerNorm.
// Block = 4 waves x 16 nodes; barrier-free, B frags L2-broadcast.
__global__ __launch_bounds__(256) void k_out(const unsigned short* __restrict__ embh,
                     const unsigned short* __restrict__ aggh,
                     const unsigned short* __restrict__ Tb,
                     const float* __restrict__ tb,
                     const float* __restrict__ gamma, const float* __restrict__ beta,
                     float* __restrict__ out){
  int t = threadIdx.x;
  int w = t >> 6;
  int lane = t & 63;
  int m16 = lane & 15;
  int q = lane >> 4;                         // 0..3
  int nodebase = blockIdx.x * 64 + w * 16;
  int nA = nodebase + m16;
  int nAc = (nA < NN) ? nA : 0;              // clamp loads; stores guarded
  floatx4 acc[8];
  #pragma unroll
  for (int ct = 0; ct < 8; ++ct) acc[ct] = (floatx4){0.f, 0.f, 0.f, 0.f};

  #pragma unroll
  for (int kc = 0; kc < 8; ++kc){
    int k0 = kc*32 + q*8;
    const unsigned short* aptr = (kc < 4) ? (embh + nAc*DIM + k0)
                                          : (aggh + nAc*DIM + (k0 - 128));
    short8_t afrag = *(const short8_t*)aptr;           // A[m=m16][k0..k0+7]
    #pragma unroll
    for (int ct = 0; ct < 8; ++ct){
      short8_t bfrag = *(const short8_t*)(Tb + (ct*16 + m16)*256 + k0); // B[k][j]=T[j][k]
      acc[ct] = __builtin_amdgcn_mfma_f32_16x16x32_bf16(afrag, bfrag, acc[ct], 0, 0, 0);
    }
  }

  float tbv[8], gmv[8], btv[8];
  #pragma unroll
  for (int ct = 0; ct < 8; ++ct){
    int col = ct*16 + m16;
    tbv[ct] = tb[col]; gmv[ct] = gamma[col]; btv[ct] = beta[col];
  }
  #pragma unroll
  for (int r = 0; r < 4; ++r){
    int n = nodebase + q*4 + r;              // D row = q*4 + reg
    float h[8]; float s = 0.f, ss = 0.f;
    #pragma unroll
    for (int ct = 0; ct < 8; ++ct){
      h[ct] = acc[ct][r] + tbv[ct];
      s += h[ct]; ss += h[ct]*h[ct];
    }
    #pragma unroll
    for (int off = 1; off < 16; off <<= 1){
      s  += __shfl_xor(s,  off, 16);
      ss += __shfl_xor(ss, off, 16);
    }
    float mu = s * (1.f/128.f);
    float var = ss * (1.f/128.f) - mu*mu;
    float rstd = rsqrtf(var + 1e-5f);
    if (n < NN){
      #pragma unroll
      for (int ct = 0; ct < 8; ++ct){
        out[n*DIM + ct*16 + m16] = (h[ct]-mu)*rstd*gmv[ct] + btv[ct];
      }
    }
  }
}

extern "C" void kernel_launch(void* const* d_in, const int* in_sizes, int n_in,
                              void* d_out, int out_size, void* d_ws, size_t ws_size,
                              hipStream_t stream){
  const float* emb          = (const float*)d_in[0];
  const int*   edges        = (const int*)d_in[1];
  const float* w_weight     = (const float*)d_in[2];
  const float* w_bias       = (const float*)d_in[3];
  const float* a_weight     = (const float*)d_in[4];
  const float* a_bias       = (const float*)d_in[5];
  const float* trans_weight = (const float*)d_in[6];
  const float* trans_bias   = (const float*)d_in[7];
  const float* ln_gamma     = (const float*)d_in[8];
  const float* ln_beta      = (const float*)d_in[9];
  float* out = (float*)d_out;

  // ws layout (float offsets) — all regions DISJOINT:
  // [0       ) p1      50,000
  // [50000   ) p2      50,000
  // [100000  ) v12c       320
  // [100320  ) ints: count[800,000 padded] rowptr[50064] bsum[64] rank[800k]  (ends 1750448)
  // [1750448 ) csr int2[800k] = 1.6M ints                            (ends 3350448)
  // [3350448 ) embh bf16[6.4M] = 3.2M floats                         (ends 6550448)
  // [6550448 ) Tb bf16[32768] = 16384 floats                         (ends 6566832)
  // [6566832 ) aggh bf16[6.4M] = 3.2M floats                         (ends 9766832)
  // [9766832 ) embf8 u32[1.6M]                                       (ends 11366832 = 45.5 MB)
  float* ws      = (float*)d_ws;
  float* p1      = ws;
  float* p2      = ws + 50000;
  float* v12c    = ws + 100000;
  int*   ibase   = (int*)(ws + 100320);
  int*   count   = ibase;                    // padded: counter d at count[d<<4]
  int*   rowptr  = ibase + 800000;
  int*   bsum    = ibase + 850064;
  int*   rank    = ibase + 850128;
  int2*  csr     = (int2*)(ws + 1750448);
  unsigned short* embh  = (unsigned short*)(ws + 3350448);
  unsigned short* Tb    = (unsigned short*)(ws + 6550448);
  unsigned short* aggh  = (unsigned short*)(ws + 6566832);
  unsigned int*   embf8 = (unsigned int*)(ws + 9766832);

  const int* e_dst = edges;
  const int* e_src = edges + NE;

  k_setup<<<3158, 256, 0, stream>>>(w_weight, w_bias, a_weight, a_bias, v12c,
                                    (const float4*)trans_weight, (ushort4*)Tb, count);
  k_pvec<<<(NN + 7)/8, 256, 0, stream>>>((const float4*)emb, v12c, p1, p2,
                                         embh, embf8, e_dst, count, rank);
  k_scanA<<<SCAN_BLK, 1024, 0, stream>>>(count, rowptr, bsum);
  k_scatter<<<(NE + 255)/256, 256, 0, stream>>>(e_dst, e_src, rank, rowptr, bsum,
                                                p1, p2, csr);
  k_gather<<<(NN + 3)/4, 256, 0, stream>>>(rowptr, bsum, csr, embf8, aggh);
  k_out<<<(NN + 63)/64, 256, 0, stream>>>(embh, aggh, Tb, trans_bias,
                                          ln_gamma, ln_beta, out);
}